// Round 5
// baseline (367.870 us; speedup 1.0000x reference)
//
#include <hip/hip_runtime.h>

// Problem constants
#define BB 2
#define SS 2048
#define DD 2048
#define HH 16
#define HDIM 128
#define MTOK (BB*SS)     // 4096 token rows
#define BHH (BB*HH)      // 32 (b,h) pairs
#define NCHUNK 16        // scan chunks per (b,h): 2048/128
#define QKN (2*DD)       // fp8 qk row stride (q cols 0..2047, k cols 2048..4095)

typedef __attribute__((ext_vector_type(8))) __bf16 bf16x8;
typedef __attribute__((ext_vector_type(4))) float f32x4;
typedef __attribute__((ext_vector_type(8))) int i32x8;

__device__ __forceinline__ unsigned short f2bf(float f) {
  unsigned u = __float_as_uint(f);
  u += 0x7FFFu + ((u >> 16) & 1u);   // RNE
  return (unsigned short)(u >> 16);
}
__device__ __forceinline__ float bf2f(unsigned short s) {
  return __uint_as_float(((unsigned)s) << 16);
}
__device__ __forceinline__ unsigned char f2e4m3(float f) {
  int pk = __builtin_amdgcn_cvt_pk_fp8_f32(f, f, 0, false);
  return (unsigned char)(pk & 0xFF);
}

// async global->LDS, 16B per lane; dst must be wave-uniform base (HW adds lane*16)
#define GLOAD_LDS16(src, dst)                                                   \
  __builtin_amdgcn_global_load_lds(                                             \
      (const void __attribute__((address_space(1)))*)(src),                     \
      (void __attribute__((address_space(3)))*)(dst), 16, 0, 0)

// ---------------- converts ----------------
__global__ void cvt_x_dual(const float* __restrict__ in,
                           unsigned short* __restrict__ outb,
                           unsigned int* __restrict__ out8, int n4) {
  int i = blockIdx.x * blockDim.x + threadIdx.x;
  if (i < n4) {
    float4 v = ((const float4*)in)[i];
    ushort4 o;
    o.x = f2bf(v.x); o.y = f2bf(v.y); o.z = f2bf(v.z); o.w = f2bf(v.w);
    ((ushort4*)outb)[i] = o;
    int p0 = __builtin_amdgcn_cvt_pk_fp8_f32(v.x, v.y, 0, false);
    int p1 = __builtin_amdgcn_cvt_pk_fp8_f32(v.z, v.w, 0, false);
    out8[i] = (unsigned)(p0 & 0xFFFF) | ((unsigned)(p1 & 0xFFFF) << 16);
  }
}

__global__ void cvt_wqk8(const float* __restrict__ a, const float* __restrict__ b,
                         unsigned int* __restrict__ out) {
  int i = blockIdx.x * blockDim.x + threadIdx.x;  // < 2<<20
  int sel = i >> 20, r = i & 0xFFFFF;             // DD*DD/4 == 1<<20
  const float* src = sel == 0 ? a : b;
  float4 v = ((const float4*)src)[r];
  int p0 = __builtin_amdgcn_cvt_pk_fp8_f32(v.x, v.y, 0, false);
  int p1 = __builtin_amdgcn_cvt_pk_fp8_f32(v.z, v.w, 0, false);
  out[i] = (unsigned)(p0 & 0xFFFF) | ((unsigned)(p1 & 0xFFFF) << 16);
}

__global__ void cvt_w2bf(const float* __restrict__ a, const float* __restrict__ b,
                         unsigned short* __restrict__ out) {
  int i = blockIdx.x * blockDim.x + threadIdx.x;  // < 2<<20
  int sel = i >> 20, r = i & 0xFFFFF;
  const float* src = sel == 0 ? a : b;
  float4 v = ((const float4*)src)[r];
  ushort4 o;
  o.x = f2bf(v.x); o.y = f2bf(v.y); o.z = f2bf(v.z); o.w = f2bf(v.w);
  ((ushort4*)out)[i] = o;
}

__global__ void concat2(const float* __restrict__ a, const float* __restrict__ b,
                        float* __restrict__ out) {
  int i = blockIdx.x * blockDim.x + threadIdx.x;
  if (i < DD) { out[i] = a[i]; out[DD + i] = b[i]; }
}

// ---------------- bf16 GEMM (round-2 form) ----------------
template <bool OUT_BF16>
__global__ __launch_bounds__(256, 2) void gemm_bt(
    const __bf16* __restrict__ A, const __bf16* __restrict__ W,
    const float* __restrict__ bias, void* __restrict__ Cout,
    int M, int N, int K) {
  __shared__ __bf16 lA[128 * 32];
  __shared__ __bf16 lB[128 * 32];
  const int t = threadIdx.x;
  const int lane = t & 63, wave = t >> 6;
  const int quad = lane >> 4, l16 = lane & 15;
  const int m0 = blockIdx.y * 128, n0 = blockIdx.x * 128;
  const int wm = (wave & 1) * 64, wn = (wave >> 1) * 64;

  f32x4 acc[4][4] = {};

  for (int k0 = 0; k0 < K; k0 += 32) {
#pragma unroll
    for (int c = 0; c < 2; ++c) {
      int lin = c * 256 + t;
      int row = lin >> 2;
      int col = (lin & 3) * 8;
      const __bf16* srcA = A + (size_t)(m0 + row) * K + k0 + col;
      const __bf16* srcB = W + (size_t)(n0 + row) * K + k0 + col;
      GLOAD_LDS16(srcA, &lA[(c * 256 + wave * 64) * 8]);
      GLOAD_LDS16(srcB, &lB[(c * 256 + wave * 64) * 8]);
    }
    __syncthreads();
    bf16x8 af[4], bfr[4];
#pragma unroll
    for (int mt = 0; mt < 4; ++mt)
      af[mt] = *(const bf16x8*)&lA[(wm + mt * 16 + l16) * 32 + quad * 8];
#pragma unroll
    for (int nt = 0; nt < 4; ++nt)
      bfr[nt] = *(const bf16x8*)&lB[(wn + nt * 16 + l16) * 32 + quad * 8];
#pragma unroll
    for (int mt = 0; mt < 4; ++mt)
#pragma unroll
      for (int nt = 0; nt < 4; ++nt)
        acc[mt][nt] = __builtin_amdgcn_mfma_f32_16x16x32_bf16(af[mt], bfr[nt],
                                                              acc[mt][nt], 0, 0, 0);
    __syncthreads();
  }

#pragma unroll
  for (int mt = 0; mt < 4; ++mt) {
#pragma unroll
    for (int nt = 0; nt < 4; ++nt) {
      int col = n0 + wn + nt * 16 + l16;
      float bv = bias[col];
#pragma unroll
      for (int r = 0; r < 4; ++r) {
        int row = m0 + wm + mt * 16 + quad * 4 + r;
        float v = acc[mt][nt][r] + bv;
        if constexpr (OUT_BF16)
          ((unsigned short*)Cout)[(size_t)row * N + col] = f2bf(v);
        else
          ((float*)Cout)[(size_t)row * N + col] = v;
      }
    }
  }
}

// ---------------- fp8 MX GEMM: C8 = e4m3( A8 @ W8^T + bias ) ----------------
__global__ __launch_bounds__(256, 2) void gemm_qk_fp8(
    const unsigned char* __restrict__ A8, const unsigned char* __restrict__ W8,
    const float* __restrict__ bias, unsigned char* __restrict__ Cout,
    int M, int N, int K) {
  __shared__ unsigned char lA[128 * 128];
  __shared__ unsigned char lB[128 * 128];
  const int t = threadIdx.x;
  const int lane = t & 63, wave = t >> 6;
  const int quad = lane >> 4, l16 = lane & 15;
  const int m0 = blockIdx.y * 128, n0 = blockIdx.x * 128;
  const int wm = (wave & 1) * 64, wn = (wave >> 1) * 64;

  f32x4 acc[4][4] = {};

  for (int k0 = 0; k0 < K; k0 += 128) {
#pragma unroll
    for (int c = 0; c < 4; ++c) {
      int lin = c * 256 + t;
      int row = lin >> 3;
      int ch = lin & 7;
      const unsigned char* srcA = A8 + (size_t)(m0 + row) * K + k0 + ch * 16;
      const unsigned char* srcB = W8 + (size_t)(n0 + row) * K + k0 + ch * 16;
      GLOAD_LDS16(srcA, &lA[(c * 256 + wave * 64) * 16]);
      GLOAD_LDS16(srcB, &lB[(c * 256 + wave * 64) * 16]);
    }
    __syncthreads();
    i32x8 af[4];
#pragma unroll
    for (int mt = 0; mt < 4; ++mt)
      af[mt] = *(const i32x8*)&lA[(wm + mt * 16 + l16) * 128 + quad * 32];
#pragma unroll
    for (int nt = 0; nt < 4; ++nt) {
      i32x8 bfr = *(const i32x8*)&lB[(wn + nt * 16 + l16) * 128 + quad * 32];
#pragma unroll
      for (int mt = 0; mt < 4; ++mt)
        acc[mt][nt] = __builtin_amdgcn_mfma_scale_f32_16x16x128_f8f6f4(
            af[mt], bfr, acc[mt][nt], 0, 0, 0, 127, 0, 127);
    }
    __syncthreads();
  }

#pragma unroll
  for (int mt = 0; mt < 4; ++mt) {
#pragma unroll
    for (int nt = 0; nt < 4; ++nt) {
      int col = n0 + wn + nt * 16 + l16;
      float bv = bias[col];
#pragma unroll
      for (int r = 0; r < 4; ++r) {
        int row = m0 + wm + mt * 16 + quad * 4 + r;
        Cout[(size_t)row * N + col] = f2e4m3(acc[mt][nt][r] + bv);
      }
    }
  }
}

// ---------------- QK^T upper-tri exp row-sums + diagonal (MX, restructured) ----
// Grid (32, BHH): blockIdx.x = pair p (0..15) + half hf (0/1).
//   hf=0: i-tile p, first 9 j-tiles (starts at diagonal tile) -> denomA(+i), diag
//   hf=1: segA: i-tile p, remaining 7-p/2 j-tiles -> denomB
//         segB: i-tile 31-p, all its 16-(31-p)/2 j-tiles (starts at diag)
//               -> denomA(+i), diag; also denomB=0 for those rows
// Waves own 32-col strips (B-LDS reads 4x fewer); Q frags for all 64 rows in regs.
// MX 16x16x128 MFMA, unit scales. LDS rows 128B with ch^(row&7) swizzle -> <=2-way.
__global__ __launch_bounds__(256, 4) void qk_rowsum_mx(
    const unsigned char* __restrict__ q8, const unsigned char* __restrict__ k8,
    float* __restrict__ denomA, float* __restrict__ denomB,
    float* __restrict__ diag) {
  __shared__ unsigned char lK[128 * 128];  // 16 KB
  __shared__ float lred[2 * 256];          // rowsum | diag partials
  const int t = threadIdx.x;
  const int lane = t & 63, wave = t >> 6;
  const int quad = lane >> 4, l16 = lane & 15;
  const int bh = blockIdx.y;
  const int b = bh >> 4, h = bh & 15;
  const int p = blockIdx.x & 15, hf = blockIdx.x >> 4;
  const float SL2E = 0.03188233603f;  // (1/sqrt(2048)) * log2(e)

  const int nseg = hf ? 2 : 1;
  for (int si = 0; si < nseg; ++si) {
    int q, jt0, cnt, mode;  // mode bit0: denomA+diag, bit1: denomB=total, bit2: denomB=0
    bool dg;
    if (hf == 0)      { q = p;      jt0 = p >> 1;       cnt = 9;             dg = true;  mode = 1; }
    else if (si == 0) { q = p;      jt0 = (p >> 1) + 9; cnt = 7 - (p >> 1);  dg = false; mode = 2; }
    else              { q = 31 - p; jt0 = q >> 1;       cnt = 16 - (q >> 1); dg = true;  mode = 5; }

    // Q fragments: all 64 rows of i-tile q (32B/lane, one MX k-block per quad)
    i32x8 af[4];
#pragma unroll
    for (int mt = 0; mt < 4; ++mt)
      af[mt] = *(const i32x8*)(q8 + (size_t)(b * SS + q * 64 + mt * 16 + l16) * QKN
                               + h * HDIM + quad * 32);

    float rs[4][4] = {};
    float dv[4][4] = {};

    for (int jt = jt0; jt < jt0 + cnt; ++jt) {
      const int j0 = jt * 128;
      // stage K-tile [128 rows][128B], ch-xor swizzled
#pragma unroll
      for (int c = 0; c < 4; ++c) {
        int L = c * 256 + t;
        int row = L >> 3, ch = L & 7;
        const unsigned char* src = k8 + (size_t)(b * SS + j0 + row) * QKN
                                   + h * HDIM + ((ch ^ (row & 7)) * 16);
        GLOAD_LDS16(src, &lK[(c * 256 + wave * 64) * 16]);
      }
      __syncthreads();
      const bool masked = dg && (jt == jt0);
#pragma unroll
      for (int ntl = 0; ntl < 2; ++ntl) {
        int jrow = (wave * 2 + ntl) * 16 + l16;  // col within tile, 0..127
        uint4 lo = *(const uint4*)&lK[jrow * 128 + (((quad * 2) ^ (jrow & 7)) * 16)];
        uint4 hi = *(const uint4*)&lK[jrow * 128 + (((quad * 2 + 1) ^ (jrow & 7)) * 16)];
        i32x8 bfr;
        bfr[0] = lo.x; bfr[1] = lo.y; bfr[2] = lo.z; bfr[3] = lo.w;
        bfr[4] = hi.x; bfr[5] = hi.y; bfr[6] = hi.z; bfr[7] = hi.w;
        f32x4 sacc[4];
#pragma unroll
        for (int mt = 0; mt < 4; ++mt) {
          f32x4 z = {0.f, 0.f, 0.f, 0.f};
          sacc[mt] = __builtin_amdgcn_mfma_scale_f32_16x16x128_f8f6f4(
              af[mt], bfr, z, 0, 0, 0, 127, 0, 127);
        }
        int colg = j0 + jrow;
        if (masked) {
#pragma unroll
          for (int mt = 0; mt < 4; ++mt)
#pragma unroll
            for (int r = 0; r < 4; ++r) {
              int rg = q * 64 + mt * 16 + quad * 4 + r;
              float e = exp2f(sacc[mt][r] * SL2E);
              if (colg >= rg) rs[mt][r] += e;
              if (colg == rg) dv[mt][r] = e;
            }
        } else {
#pragma unroll
          for (int mt = 0; mt < 4; ++mt)
#pragma unroll
            for (int r = 0; r < 4; ++r)
              rs[mt][r] += exp2f(sacc[mt][r] * SL2E);
        }
      }
      __syncthreads();  // protect lK before restage
    }

    // 16-lane col reduce, then cross-wave combine via LDS
#pragma unroll
    for (int mt = 0; mt < 4; ++mt)
#pragma unroll
      for (int r = 0; r < 4; ++r) {
        float s = rs[mt][r], d = dv[mt][r];
#pragma unroll
        for (int off = 1; off < 16; off <<= 1) {
          s += __shfl_xor(s, off, 64);
          d += __shfl_xor(d, off, 64);
        }
        if (l16 == 0) {
          int rl = mt * 16 + quad * 4 + r;
          lred[wave * 64 + rl] = s;
          lred[256 + wave * 64 + rl] = d;
        }
      }
    __syncthreads();
    if (t < 64) {
      float tot = lred[t] + lred[64 + t] + lred[128 + t] + lred[192 + t];
      float dtot = lred[256 + t] + lred[320 + t] + lred[384 + t] + lred[448 + t];
      int rg = q * 64 + t;
      if (mode & 1) {
        denomA[bh * SS + rg] = (float)rg + tot;
        diag[bh * SS + rg] = dtot;
      }
      if (mode & 2) denomB[bh * SS + rg] = tot;
      if (mode & 4) denomB[bh * SS + rg] = 0.f;
    }
    __syncthreads();  // lred/lK reuse by next segment
  }
}

// ---------------- V prefix-scan, two-pass, 16B/lane ----------------
__global__ void scan_pass1(const __bf16* __restrict__ v0,
                           float* __restrict__ csum) {
  int blk = blockIdx.x;
  int bh = blk >> 4, c = blk & 15;
  int b = bh >> 4, h = bh & 15;
  int t = threadIdx.x;
  int rs = t >> 4, dg = t & 15;
  const unsigned short* base = (const unsigned short*)v0 +
      (size_t)(b * SS + c * 128 + rs * 8) * DD + h * HDIM + dg * 8;
  float s[8] = {0.f, 0.f, 0.f, 0.f, 0.f, 0.f, 0.f, 0.f};
#pragma unroll
  for (int i = 0; i < 8; ++i) {
    uint4 u = *(const uint4*)(base + (size_t)i * DD);
    const unsigned short* us = (const unsigned short*)&u;
#pragma unroll
    for (int j = 0; j < 8; ++j) s[j] += bf2f(us[j]);
  }
  __shared__ float red[16 * 128];
#pragma unroll
  for (int j = 0; j < 8; ++j) red[rs * 128 + dg * 8 + j] = s[j];
  __syncthreads();
  for (int st = 8; st >= 1; st >>= 1) {
    if (rs < st) {
#pragma unroll
      for (int j = 0; j < 8; ++j)
        red[rs * 128 + dg * 8 + j] += red[(rs + st) * 128 + dg * 8 + j];
    }
    __syncthreads();
  }
  if (rs == 0) {
#pragma unroll
    for (int j = 0; j < 8; ++j)
      csum[(size_t)blk * 128 + dg * 8 + j] = red[dg * 8 + j];
  }
}

__global__ void scan_pass2(const __bf16* __restrict__ v0,
                           const float* __restrict__ csum,
                           const float* __restrict__ denomA,
                           const float* __restrict__ denomB,
                           const float* __restrict__ diag,
                           unsigned short* __restrict__ ctx) {
  int blk = blockIdx.x;
  int bh = blk >> 4, c = blk & 15;
  int b = bh >> 4, h = bh & 15;
  int t = threadIdx.x;
  int rs = t >> 4, dg = t & 15;
  const unsigned short* vbase = (const unsigned short*)v0 +
      (size_t)(b * SS + c * 128 + rs * 8) * DD + h * HDIM + dg * 8;
  float vrow[8][8];
  float ls[8] = {0.f, 0.f, 0.f, 0.f, 0.f, 0.f, 0.f, 0.f};
#pragma unroll
  for (int i = 0; i < 8; ++i) {
    uint4 u = *(const uint4*)(vbase + (size_t)i * DD);
    const unsigned short* us = (const unsigned short*)&u;
#pragma unroll
    for (int j = 0; j < 8; ++j) {
      vrow[i][j] = bf2f(us[j]);
      ls[j] += vrow[i][j];
    }
  }
  __shared__ float red[16 * 128];
#pragma unroll
  for (int j = 0; j < 8; ++j) red[rs * 128 + dg * 8 + j] = ls[j];
  __syncthreads();

  float pre[8] = {0.f, 0.f, 0.f, 0.f, 0.f, 0.f, 0.f, 0.f};
  for (int cc = 0; cc < c; ++cc) {
    const float* cp = csum + (size_t)(bh * 16 + cc) * 128 + dg * 8;
#pragma unroll
    for (int j = 0; j < 8; ++j) pre[j] += cp[j];
  }
  for (int ss2 = 0; ss2 < rs; ++ss2) {
#pragma unroll
    for (int j = 0; j < 8; ++j) pre[j] += red[ss2 * 128 + dg * 8 + j];
  }

  int row0 = c * 128 + rs * 8;
  unsigned short* obase =
      ctx + (size_t)(b * SS + row0) * DD + h * HDIM + dg * 8;
  const float* dnA = denomA + bh * SS + row0;
  const float* dnB = denomB + bh * SS + row0;
  const float* dgp = diag + bh * SS + row0;
#pragma unroll
  for (int i = 0; i < 8; ++i) {
    float inv = 1.0f / (dnA[i] + dnB[i]);
    float dvv = dgp[i];
    unsigned short o[8];
#pragma unroll
    for (int j = 0; j < 8; ++j) {
      float val = (pre[j] + dvv * vrow[i][j]) * inv;
      o[j] = f2bf(val);
      pre[j] += vrow[i][j];
    }
    *(uint4*)(obase + (size_t)i * DD) = *(const uint4*)o;
  }
}

extern "C" void kernel_launch(void* const* d_in, const int* in_sizes, int n_in,
                              void* d_out, int out_size, void* d_ws, size_t ws_size,
                              hipStream_t stream) {
  (void)in_sizes; (void)n_in; (void)out_size; (void)ws_size;
  const float* x    = (const float*)d_in[0];
  const float* wq_w = (const float*)d_in[1];
  const float* wq_b = (const float*)d_in[2];
  const float* wk_w = (const float*)d_in[3];
  const float* wk_b = (const float*)d_in[4];
  const float* wv_w = (const float*)d_in[5];
  const float* wv_b = (const float*)d_in[6];
  const float* wo_w = (const float*)d_in[7];
  const float* wo_b = (const float*)d_in[8];

  char* ws = (char*)d_ws;
  size_t off = 0;
  auto alloc = [&](size_t bytes) {
    char* p = ws + off;
    off += (bytes + 255) & ~(size_t)255;
    return p;
  };
  unsigned short* xb   = (unsigned short*)alloc((size_t)MTOK * DD * 2);    // 16 MB
  unsigned char*  x8   = (unsigned char*)alloc((size_t)MTOK * DD);         // 8 MB
  unsigned char*  wqk8 = (unsigned char*)alloc((size_t)2 * DD * DD);       // 8 MB
  unsigned short* wvo  = (unsigned short*)alloc((size_t)2 * DD * DD * 2);  // 16 MB (wv | wo)
  unsigned char*  qk8  = (unsigned char*)alloc((size_t)MTOK * QKN);        // 16 MB
  unsigned short* v    = (unsigned short*)alloc((size_t)MTOK * DD * 2);    // 16 MB
  unsigned short* ctx  = (unsigned short*)alloc((size_t)MTOK * DD * 2);    // 16 MB
  float* biasqk = (float*)alloc((size_t)2 * DD * 4);
  float* denomA = (float*)alloc((size_t)BHH * SS * 4);
  float* denomB = (float*)alloc((size_t)BHH * SS * 4);
  float* diag   = (float*)alloc((size_t)BHH * SS * 4);
  float* csum   = (float*)alloc((size_t)BHH * NCHUNK * 128 * 4);

  // 1) converts
  {
    int n4 = MTOK * DD / 4;
    cvt_x_dual<<<n4 / 256, 256, 0, stream>>>(x, xb, (unsigned int*)x8, n4);
    cvt_wqk8<<<(2 << 20) / 256, 256, 0, stream>>>(wq_w, wk_w, (unsigned int*)wqk8);
    cvt_w2bf<<<(2 << 20) / 256, 256, 0, stream>>>(wv_w, wo_w, wvo);
    concat2<<<(DD + 255) / 256, 256, 0, stream>>>(wq_b, wk_b, biasqk);
  }

  // 2) QK projection, MX-fp8 -> qk8 [4096][4096] e4m3
  gemm_qk_fp8<<<dim3(QKN / 128, MTOK / 128), 256, 0, stream>>>(
      x8, wqk8, biasqk, qk8, MTOK, QKN, DD);

  // 3) V projection in bf16 -> v [4096][2048]
  gemm_bt<true><<<dim3(DD / 128, MTOK / 128), 256, 0, stream>>>(
      (const __bf16*)xb, (const __bf16*)wvo, wv_b, v, MTOK, DD, DD);

  // 4) denominators + diagonal exps (MX MFMA, split-balanced, 1024 blocks)
  qk_rowsum_mx<<<dim3(32, BHH), 256, 0, stream>>>(
      qk8,            // q at col 0
      qk8 + DD,       // k at col 2048
      denomA, denomB, diag);

  // 5) V scan -> ctx
  scan_pass1<<<BHH * NCHUNK, 256, 0, stream>>>((const __bf16*)v, csum);
  scan_pass2<<<BHH * NCHUNK, 256, 0, stream>>>((const __bf16*)v, csum,
                                               denomA, denomB, diag, ctx);

  // 6) output projection -> d_out fp32
  gemm_bt<false><<<dim3(DD / 128, MTOK / 128), 256, 0, stream>>>(
      (const __bf16*)ctx, (const __bf16*)(wvo + (size_t)DD * DD), wo_b,
      d_out, MTOK, DD, DD);
}